// Round 4
// baseline (99.708 us; speedup 1.0000x reference)
//
#include <hip/hip_runtime.h>

// LogSig_var: depth-2 log-signature over 64 segments of ragged paths.
// inp:    (256, 2048, 12) fp32
// length: (256,) int32, 1..2048
// out:    (256, 64, 78) fp32   [12 increments + 66 Levy areas (i<j lex order)]
//
// Per-segment algebra (segments independent, no cumsum needed):
//   inc_i  = Xb_i - Xa_i
//   levy_p = 0.5*( sum_{t=a}^{b-1} [X_i(t)X_j(t+1) - X_j(t)X_i(t+1)]
//                  - (Xa_i*Xb_j - Xa_j*Xb_i) )
//
// R3 change: 8 blocks/batch with CONSECUTIVE mapping (blockIdx = batch*8+oct).
// R2's quarter=blockIdx>>8 put a batch's blocks at stride 256 == same CU
// (round-robin period 8 XCD x 32 CU = 256) -> straggler blocks piled onto one
// CU, no speedup. Consecutive blocks go to consecutive XCDs -> a straggler's
// 8 blocks run on 8 different CUs; critical path = 1 loop iteration
// (32 steps / 32 lanes) + 5-level shuffle reduction.

#define BATCH 256
#define TLEN 2048
#define DCH 12
#define NSEG 64
#define NPAIR 66          // d*(d-1)/2
#define NCH 78            // 12 + 66
#define SEG_PER_BLK 8
#define LANES_PER_SEG 32

__device__ __forceinline__ int tv_round(int j, int Lf) {
    // round-half-even(1 + j*Lf/64), exact. q = j*Lf <= 64*2047 < 2^17.
    int q = j * Lf;
    int base = 1 + (q >> 6);
    int r = q & 63;
    int up = (r > 32) || (r == 32 && (base & 1));
    return base + up;
}

__device__ __forceinline__ void load_row(const float* __restrict__ X, int r,
                                         float* __restrict__ v) {
    const float4* p = (const float4*)(X + r * DCH);
    float4 f0 = p[0], f1 = p[1], f2 = p[2];
    v[0] = f0.x; v[1] = f0.y; v[2]  = f0.z; v[3]  = f0.w;
    v[4] = f1.x; v[5] = f1.y; v[6]  = f1.z; v[7]  = f1.w;
    v[8] = f2.x; v[9] = f2.y; v[10] = f2.z; v[11] = f2.w;
}

__global__ __launch_bounds__(256) void logsig_kernel(
        const float* __restrict__ inp,
        const int* __restrict__ length,
        float* __restrict__ out) {
    __shared__ __align__(16) float lds_out[SEG_PER_BLK * NCH];  // 2496 B

    const int batch = blockIdx.x >> 3;
    const int octant = blockIdx.x & 7;   // consecutive -> different XCDs
    const int tid = threadIdx.x;
    const int L = length[batch];

    const float* __restrict__ X = inp + (size_t)batch * TLEN * DCH;

    // ---- segment assignment: 32 contiguous lanes per segment ----
    const int lane = tid & 63;
    const int wave = tid >> 6;                     // 0..3
    const int seg_local = wave * 2 + (lane >> 5);  // 0..7
    const int seg = octant * SEG_PER_BLK + seg_local;
    const int q32 = lane & 31;

    const bool expand = (L < NSEG + 1);
    const int k = expand ? (NSEG / L + 1) : 1;
    const int Leff = expand ? k * L : L;
    const int Lf = Leff - 1;

    const int a = tv_round(seg, Lf) - 1;
    const int b = tv_round(seg + 1, Lf) - 1;

    float acc[NPAIR];
#pragma unroll
    for (int p = 0; p < NPAIR; ++p) acc[p] = 0.0f;

    for (int t = a + q32; t < b; t += LANES_PER_SEG) {
        int r0, r1;
        if (expand) {
            r0 = min(t / k, L - 1);
            r1 = min((t + 1) / k, L - 1);
        } else {
            r0 = t;
            r1 = t + 1;
        }
        float x[DCH], y[DCH];
        load_row(X, r0, x);
        load_row(X, r1, y);
        int p = 0;
#pragma unroll
        for (int i = 0; i < DCH - 1; ++i)
#pragma unroll
            for (int jj = i + 1; jj < DCH; ++jj) {
                acc[p] = fmaf(x[i], y[jj], acc[p]);
                acc[p] = fmaf(-x[jj], y[i], acc[p]);
                ++p;
            }
    }

    // ---- reduce 32 lanes of each segment (xor<=16 stays in the half) ----
#pragma unroll
    for (int p = 0; p < NPAIR; ++p) {
        acc[p] += __shfl_xor(acc[p], 1, 64);
        acc[p] += __shfl_xor(acc[p], 2, 64);
        acc[p] += __shfl_xor(acc[p], 4, 64);
        acc[p] += __shfl_xor(acc[p], 8, 64);
        acc[p] += __shfl_xor(acc[p], 16, 64);
    }

    // ---- writer lane: boundary term + store channels to LDS ----
    if (q32 == 0) {
        int ra, rb;
        if (expand) {
            ra = min(a / k, L - 1);
            rb = min(b / k, L - 1);
        } else {
            ra = a;
            rb = b;
        }
        float xa[DCH], xb[DCH];
        load_row(X, ra, xa);
        load_row(X, rb, xb);
        float* o = lds_out + seg_local * NCH;
#pragma unroll
        for (int i = 0; i < DCH; ++i) o[i] = xb[i] - xa[i];
        int p = 0;
#pragma unroll
        for (int i = 0; i < DCH - 1; ++i)
#pragma unroll
            for (int jj = i + 1; jj < DCH; ++jj) {
                o[DCH + p] = 0.5f * (acc[p] - (xa[i] * xb[jj] - xa[jj] * xb[i]));
                ++p;
            }
    }
    __syncthreads();

    // ---- coalesced copy-out: 8*78 = 624 floats = 156 float4 ----
    {
        float4* od = (float4*)(out + (size_t)batch * NSEG * NCH
                               + (size_t)octant * SEG_PER_BLK * NCH);
        const float4* os = (const float4*)lds_out;
        if (tid < (SEG_PER_BLK * NCH) / 4) od[tid] = os[tid];
    }
}

extern "C" void kernel_launch(void* const* d_in, const int* in_sizes, int n_in,
                              void* d_out, int out_size, void* d_ws, size_t ws_size,
                              hipStream_t stream) {
    const float* inp = (const float*)d_in[0];
    const int* length = (const int*)d_in[1];
    float* out = (float*)d_out;
    logsig_kernel<<<BATCH * 8, 256, 0, stream>>>(inp, length, out);
}

// Round 5
// 74.017 us; speedup vs baseline: 1.3471x; 1.3471x over previous
//
#include <hip/hip_runtime.h>

// LogSig_var: depth-2 log-signature over 64 segments of ragged paths.
// inp:    (256, 2048, 12) fp32
// length: (256,) int32, 1..2048
// out:    (256, 64, 78) fp32   [12 increments + 66 Levy areas (i<j lex order)]
//
// Per-segment algebra (segments independent, no cumsum needed):
//   inc_i  = Xb_i - Xa_i
//   levy_p = 0.5*( sum_{t=a}^{b-1} [X_i(t)X_j(t+1) - X_j(t)X_i(t+1)]
//                  - (Xa_i*Xb_j - Xa_j*Xb_i) )
//
// R4: revert to R1 config (1 block/batch, 4 lanes/seg, 2 shfl levels) —
// measured best. R2/R3 showed dur scales with per-CU reduction DS-instr
// count (528/4224/10560 -> 75.1/82.4/99.7 us): wide per-segment lane splits
// multiply the 66-channel shuffle reduction; 4 lanes/seg is the optimum.
// Micro-opts this round: (a) manual load rotation (prefetch next iter's rows
// before this iter's 132 FMAs -> hide LLC latency the compiler can't rotate
// across the dynamic trip-count), (b) FMA ordering kept SLP-friendly for
// v_pk_fma_f32 packing (consecutive acc[p], shared x[i] multiplier).

#define BATCH 256
#define TLEN 2048
#define DCH 12
#define NSEG 64
#define NPAIR 66          // d*(d-1)/2
#define NCH 78            // 12 + 66

__device__ __forceinline__ int tv_round(int j, int Lf) {
    // round-half-even(1 + j*Lf/64), exact. q = j*Lf <= 64*2047 < 2^17.
    int q = j * Lf;
    int base = 1 + (q >> 6);
    int r = q & 63;
    int up = (r > 32) || (r == 32 && (base & 1));
    return base + up;
}

__device__ __forceinline__ void load_row(const float* __restrict__ X, int r,
                                         float* __restrict__ v) {
    const float4* p = (const float4*)(X + r * DCH);
    float4 f0 = p[0], f1 = p[1], f2 = p[2];
    v[0] = f0.x; v[1] = f0.y; v[2]  = f0.z; v[3]  = f0.w;
    v[4] = f1.x; v[5] = f1.y; v[6]  = f1.z; v[7]  = f1.w;
    v[8] = f2.x; v[9] = f2.y; v[10] = f2.z; v[11] = f2.w;
}

__global__ __launch_bounds__(256) void logsig_kernel(
        const float* __restrict__ inp,
        const int* __restrict__ length,
        float* __restrict__ out) {
    __shared__ __align__(16) float lds_out[NSEG * NCH];  // 19968 B

    const int batch = blockIdx.x;
    const int tid = threadIdx.x;
    const int L = length[batch];

    const float* __restrict__ X = inp + (size_t)batch * TLEN * DCH;

    // ---- segment assignment: 4 contiguous lanes per segment ----
    const int lane = tid & 63;
    const int wave = tid >> 6;
    const int seg = wave * 16 + (lane >> 2);
    const int q4 = lane & 3;

    const bool expand = (L < NSEG + 1);
    const int k = expand ? (NSEG / L + 1) : 1;
    const int Leff = expand ? k * L : L;
    const int Lf = Leff - 1;

    const int a = tv_round(seg, Lf) - 1;
    const int b = tv_round(seg + 1, Lf) - 1;

    float acc[NPAIR];
#pragma unroll
    for (int p = 0; p < NPAIR; ++p) acc[p] = 0.0f;

    // ---- rotated (software-pipelined) step loop ----
    int t = a + q4;
    float x[DCH], y[DCH];
    if (t < b) {
        int r0, r1;
        if (expand) {
            r0 = min(t / k, L - 1);
            r1 = min((t + 1) / k, L - 1);
        } else {
            r0 = t;
            r1 = t + 1;
        }
        load_row(X, r0, x);
        load_row(X, r1, y);
    }
    while (t < b) {
        const int tn = t + 4;
        float xn[DCH], yn[DCH];
        if (tn < b) {  // prefetch next iteration's rows before the FMA block
            int r0, r1;
            if (expand) {
                r0 = min(tn / k, L - 1);
                r1 = min((tn + 1) / k, L - 1);
            } else {
                r0 = tn;
                r1 = tn + 1;
            }
            load_row(X, r0, xn);
            load_row(X, r1, yn);
        }
        int p = 0;
#pragma unroll
        for (int i = 0; i < DCH - 1; ++i) {
#pragma unroll
            for (int jj = i + 1; jj < DCH; ++jj) {
                acc[p] = fmaf(x[i], y[jj], acc[p]);   // shared x[i], consec p
                ++p;
            }
        }
        p = 0;
#pragma unroll
        for (int i = 0; i < DCH - 1; ++i) {
#pragma unroll
            for (int jj = i + 1; jj < DCH; ++jj) {
                acc[p] = fmaf(-x[jj], y[i], acc[p]);  // shared y[i], consec p
                ++p;
            }
        }
#pragma unroll
        for (int c = 0; c < DCH; ++c) { x[c] = xn[c]; y[c] = yn[c]; }
        t = tn;
    }

    // ---- reduce the 4 lanes of each segment (contiguous lanes -> same wave)
#pragma unroll
    for (int p = 0; p < NPAIR; ++p) {
        acc[p] += __shfl_xor(acc[p], 1, 64);
        acc[p] += __shfl_xor(acc[p], 2, 64);
    }

    // ---- writer lane: boundary term + store channels to LDS ----
    if (q4 == 0) {
        int ra, rb;
        if (expand) {
            ra = min(a / k, L - 1);
            rb = min(b / k, L - 1);
        } else {
            ra = a;
            rb = b;
        }
        float xa[DCH], xb[DCH];
        load_row(X, ra, xa);
        load_row(X, rb, xb);
        float* o = lds_out + seg * NCH;
#pragma unroll
        for (int i = 0; i < DCH; ++i) o[i] = xb[i] - xa[i];
        int p = 0;
#pragma unroll
        for (int i = 0; i < DCH - 1; ++i)
#pragma unroll
            for (int jj = i + 1; jj < DCH; ++jj) {
                o[DCH + p] = 0.5f * (acc[p] - (xa[i] * xb[jj] - xa[jj] * xb[i]));
                ++p;
            }
    }
    __syncthreads();

    // ---- coalesced copy-out: 64*78 = 4992 floats = 1248 float4 ----
    {
        float4* od = (float4*)(out + (size_t)batch * NSEG * NCH);
        const float4* os = (const float4*)lds_out;
        for (int i = tid; i < (NSEG * NCH) / 4; i += 256) od[i] = os[i];
    }
}

extern "C" void kernel_launch(void* const* d_in, const int* in_sizes, int n_in,
                              void* d_out, int out_size, void* d_ws, size_t ws_size,
                              hipStream_t stream) {
    const float* inp = (const float*)d_in[0];
    const int* length = (const int*)d_in[1];
    float* out = (float*)d_out;
    logsig_kernel<<<BATCH, 256, 0, stream>>>(inp, length, out);
}